// Round 12
// baseline (290.799 us; speedup 1.0000x reference)
//
#include <hip/hip_runtime.h>

// Sparse 2:4 grouped conv, MI355X.  R12: conv reverted VERBATIM to R3 (best
// measured: 71.6 us conv / 254 us total; 5 redesigns R4-R8 all regressed).
// Prep rewritten without LDS: one pass, lane=iwp coalesced reads along iw,
// register bf16x8 pack, 16B stores (L2 merges c-quarter interleave).  Frees
// prep's 28.9 KB LDS and removes the two-pass + barrier structure.

#define INF   1152
#define HO    56
#define LOUT  3136      // 56*56
#define XP    58        // padded spatial

typedef __attribute__((ext_vector_type(8))) short bf16x8;
typedef __attribute__((ext_vector_type(4))) float f32x4;

__device__ __forceinline__ unsigned short f2bf(float f) {
  union { float f; unsigned u; } v; v.f = f;
  unsigned r = v.u + 0x7fffu + ((v.u >> 16) & 1u);   // RNE
  return (unsigned short)(r >> 16);
}

__device__ __forceinline__ void async_load16(const void* g, void* l) {
  __builtin_amdgcn_global_load_lds(
      (const __attribute__((address_space(1))) void*)g,
      (__attribute__((address_space(3))) void*)l, 16, 0, 0);
}

// ---------------- fused prep: pad+transpose+cast x  |  gumbel+mask+pack W ------
// blocks [0,3712): xpose (bg=bid/58, ihp=bid%58) — NO LDS, single pass:
//   wave w owns c-quarter w; lane l = iwp; 8 scalar coalesced reads per 8-c
//   group (224B/wave segments), pack to bf16x8, one 16B store.
// blocks [3712,4864): Wt[g][tap][of][c] pack with inline gumbel argmax (R3)
__global__ __launch_bounds__(256) void prep_kernel(
    const float* __restrict__ x, const float* __restrict__ Ws,
    const float* __restrict__ cw, const float* __restrict__ gb,
    const float* __restrict__ pat,
    unsigned short* __restrict__ Xt, unsigned short* __restrict__ Wt) {
  const int t   = threadIdx.x;
  const int bid = blockIdx.x;

  if (bid >= 3712) {                                 // ---- weight pack ----
    int idx = (bid - 3712) * 256 + t;                // 294912 total
    int c   = idx & 127;
    int of  = (idx >> 7) & 127;
    int gt  = idx >> 14;                             // g*9+tap
    int g   = gt / 9;
    int tap = gt - g * 9;
    int e   = ((g << 7) + of) * INF + c * 9 + tap;
    int q   = e >> 2, pos = e & 3;
    const float* cq = cw + q * 6;
    const float* gq = gb + q * 6;
    float best = cq[0] + gq[0]; int bi = 0;
    #pragma unroll
    for (int j = 1; j < 6; ++j) {
      float v2 = cq[j] + gq[j];
      if (v2 > best) { best = v2; bi = j; }          // strict > = first-max
    }
    Wt[idx] = f2bf(Ws[e] * pat[bi * 4 + pos]);
    return;
  }

  // ---- xpose: x (B,256,56,56) f32 -> Xt[bg][58][58][c=128] bf16, zero borders
  const int bg  = bid / 58;
  const int ihp = bid - bg * 58;
  unsigned short* dstrow = Xt + ((bg * XP + ihp) * XP) * 128;
  if (ihp == 0 || ihp == XP - 1) {                   // zero border rows
    uint4* dst = (uint4*)dstrow;
    const uint4 z = {0u, 0u, 0u, 0u};
    for (int i = t; i < XP * 16; i += 256) dst[i] = z;
    return;
  }
  const int ih = ihp - 1;
  const int w  = t >> 6, l = t & 63;                 // wave = c-quarter, lane = iwp
  if (l >= XP) return;                               // lanes 58-63 idle
  const bool interior = (l >= 1 && l <= 56);
  const int iw = l - 1;
  const float* xb = x + (bg * 128 + w * 32) * LOUT + ih * HO + iw;
  #pragma unroll
  for (int c8 = 0; c8 < 4; ++c8) {
    float v[8];
    #pragma unroll
    for (int e = 0; e < 8; ++e)
      v[e] = interior ? xb[(c8 * 8 + e) * LOUT] : 0.f;
    uint4 val;
    val.x = (unsigned)f2bf(v[0]) | ((unsigned)f2bf(v[1]) << 16);
    val.y = (unsigned)f2bf(v[2]) | ((unsigned)f2bf(v[3]) << 16);
    val.z = (unsigned)f2bf(v[4]) | ((unsigned)f2bf(v[5]) << 16);
    val.w = (unsigned)f2bf(v[6]) | ((unsigned)f2bf(v[7]) << 16);
    *(uint4*)(dstrow + l * 128 + w * 32 + c8 * 8) = val;
  }
}

// ---------------- conv: implicit-GEMM, BK=64, xor-swizzled LDS (R3 verbatim) --
// LDS row = 64 c = 8 chunks of 16B; chunk (row,ch) stored at slot ch^(row&7).
// Staging: wave issue covers 8 rows x 8 chunks = 1 KB; lane l -> row +(l>>3),
// logical ch (l&7)^(l>>3)  (matches lane-linear LDS dest constraint).
__global__ __launch_bounds__(256, 4) void conv_mfma_kernel(
    const unsigned short* __restrict__ Wt, const unsigned short* __restrict__ Xt,
    float* __restrict__ out) {
  __shared__ __align__(16) unsigned short sA[128 * 64];   // 16 KB
  __shared__ __align__(16) unsigned short sB[128 * 64];   // 16 KB
  const int t  = threadIdx.x;
  const int ln = t & 63, wv = t >> 6;
  const int wm = wv >> 1, wn = wv & 1;
  const int col = ln & 15, kq = ln >> 4, c7 = col & 7;

  // XCD-aware swizzle: contiguous bg range per XCD for L2 locality
  const int lid   = blockIdx.y * 25 + blockIdx.x;
  const int v     = (lid & 7) * 200 + (lid >> 3);
  const int bg    = v / 25;
  const int tileN = v - bg * 25;
  const int g     = bg & 1;
  const int l0    = tileN << 7;

  // staging geometry (fixed per thread)
  const int r8 = ln >> 3;                  // row within 8-row issue group
  const int ch = (ln & 7) ^ r8;            // logical 16B chunk within 64-c row
  int arow[4], brow[4];
  #pragma unroll
  for (int i = 0; i < 4; ++i) {
    const int rr = (wv << 5) + (i << 3) + r8;      // 0..127
    arow[i] = (rr << 7) + (ch << 3);               // of*128 + c
    int ll = l0 + rr;
    if (ll > LOUT - 1) ll = LOUT - 1;              // tail tile: clamp
    int oh = ll / HO, ow = ll - oh * HO;
    brow[i] = ((bg * XP + oh) * XP + ow) * 128 + (ch << 3);
  }

  f32x4 acc[4][4];
  #pragma unroll
  for (int i = 0; i < 4; ++i)
    #pragma unroll
    for (int j = 0; j < 4; ++j) acc[i][j] = (f32x4){0.f, 0.f, 0.f, 0.f};

  for (int tap = 0; tap < 9; ++tap) {
    const int th = tap / 3, tw = tap - th * 3;
    const int bTap = (th * XP + tw) << 7;
    const int aTap = (g * 9 + tap) << 14;
    #pragma unroll 1
    for (int kc = 0; kc < 2; ++kc) {
      const int c0 = kc << 6;
      __syncthreads();                             // prior reads done
      #pragma unroll
      for (int i = 0; i < 4; ++i) {
        const int lb = ((wv << 5) + (i << 3)) << 6;   // LDS elem base
        async_load16(Wt + aTap + c0 + arow[i], &sA[lb]);
        async_load16(Xt + bTap + c0 + brow[i], &sB[lb]);
      }
      __syncthreads();                             // drains vmcnt
      #pragma unroll
      for (int kh = 0; kh < 2; ++kh) {
        const int pk = (((kh << 2) + kq) ^ c7) << 3;   // swizzled chunk offset
        bf16x8 af[4], bfr[4];
        #pragma unroll
        for (int mi = 0; mi < 4; ++mi)
          af[mi] = *(const bf16x8*)&sA[(((wm << 6) + (mi << 4) + col) << 6) + pk];
        #pragma unroll
        for (int ni = 0; ni < 4; ++ni)
          bfr[ni] = *(const bf16x8*)&sB[(((wn << 6) + (ni << 4) + col) << 6) + pk];
        #pragma unroll
        for (int mi = 0; mi < 4; ++mi)
          #pragma unroll
          for (int ni = 0; ni < 4; ++ni)
            acc[mi][ni] = __builtin_amdgcn_mfma_f32_16x16x32_bf16(
                af[mi], bfr[ni], acc[mi][ni], 0, 0, 0);
      }
    }
  }

  // epilogue: C/D layout col=lane&15, row=(lane>>4)*4+reg
  const int rowq = kq << 2;
  #pragma unroll
  for (int mi = 0; mi < 4; ++mi) {
    #pragma unroll
    for (int ni = 0; ni < 4; ++ni) {
      const int l = l0 + (wn << 6) + (ni << 4) + col;
      if (l < LOUT) {
        #pragma unroll
        for (int r = 0; r < 4; ++r) {
          const int of = (wm << 6) + (mi << 4) + rowq + r;
          out[(bg * 128 + of) * LOUT + l] = acc[mi][ni][r];
        }
      }
    }
  }
}

extern "C" void kernel_launch(void* const* d_in, const int* in_sizes, int n_in,
                              void* d_out, int out_size, void* d_ws, size_t ws_size,
                              hipStream_t stream) {
  const float* x   = (const float*)d_in[0];
  const float* Ws  = (const float*)d_in[1];
  const float* cw  = (const float*)d_in[2];
  const float* gb  = (const float*)d_in[3];
  const float* pat = (const float*)d_in[4];
  float* out = (float*)d_out;

  unsigned short* Wt = (unsigned short*)d_ws;                       // 576 KB
  unsigned short* Xt = (unsigned short*)((char*)d_ws + (1 << 20));  // 52.6 MB

  prep_kernel<<<4864, 256, 0, stream>>>(x, Ws, cw, gb, pat, Xt, Wt);
  conv_mfma_kernel<<<dim3(25, 64), 256, 0, stream>>>(Wt, Xt, out);
}

// Round 13
// 255.909 us; speedup vs baseline: 1.1363x; 1.1363x over previous
//
#include <hip/hip_runtime.h>

// Sparse 2:4 grouped conv, MI355X.  R13: revert to R0/R3 baseline (best
// measured total 253.6) + two bounded micro-opts:
//  - prep pass-2 packs bf16 pairs via v_cvt_pk_bf16_f32 (1 op vs ~7, same RNE)
//  - conv wraps the MFMA cluster in s_setprio(1)/(0) (T5; 4 independent
//    blocks/CU at different phases = the regime where setprio pays, m191)
// Ledger: conv R3=71.6us local-opt (5 redesigns lost), prep R3~51us,
// fixed harness overhead ~130us (untouchable).

#define INF   1152
#define HO    56
#define LOUT  3136      // 56*56
#define XP    58        // padded spatial

typedef __attribute__((ext_vector_type(8))) short bf16x8;
typedef __attribute__((ext_vector_type(4))) float f32x4;

__device__ __forceinline__ unsigned short f2bf(float f) {
  union { float f; unsigned u; } v; v.f = f;
  unsigned r = v.u + 0x7fffu + ((v.u >> 16) & 1u);   // RNE
  return (unsigned short)(r >> 16);
}

__device__ __forceinline__ unsigned cvt_pk_bf16(float lo, float hi) {
  unsigned r;
  asm("v_cvt_pk_bf16_f32 %0, %1, %2" : "=v"(r) : "v"(lo), "v"(hi));
  return r;                                           // lo16=bf16(lo), hi16=bf16(hi)
}

__device__ __forceinline__ void async_load16(const void* g, void* l) {
  __builtin_amdgcn_global_load_lds(
      (const __attribute__((address_space(1))) void*)g,
      (__attribute__((address_space(3))) void*)l, 16, 0, 0);
}

// ---------------- fused prep: pad+transpose+cast x  |  gumbel+mask+pack W ------
// blocks [0,3712): xpose (bg=bid/58, ihp=bid%58)   [R3 LDS version]
// blocks [3712,4864): Wt[g][tap][of][c] pack with inline gumbel argmax
__global__ __launch_bounds__(256) void prep_kernel(
    const float* __restrict__ x, const float* __restrict__ Ws,
    const float* __restrict__ cw, const float* __restrict__ gb,
    const float* __restrict__ pat,
    unsigned short* __restrict__ Xt, unsigned short* __restrict__ Wt) {
  __shared__ float lds[56 * 129];
  const int t   = threadIdx.x;
  const int bid = blockIdx.x;

  if (bid >= 3712) {                                 // ---- weight pack ----
    int idx = (bid - 3712) * 256 + t;                // 294912 total
    int c   = idx & 127;
    int of  = (idx >> 7) & 127;
    int gt  = idx >> 14;                             // g*9+tap
    int g   = gt / 9;
    int tap = gt - g * 9;
    int e   = ((g << 7) + of) * INF + c * 9 + tap;
    int q   = e >> 2, pos = e & 3;
    const float* cq = cw + q * 6;
    const float* gq = gb + q * 6;
    float best = cq[0] + gq[0]; int bi = 0;
    #pragma unroll
    for (int j = 1; j < 6; ++j) {
      float v2 = cq[j] + gq[j];
      if (v2 > best) { best = v2; bi = j; }          // strict > = first-max
    }
    Wt[idx] = f2bf(Ws[e] * pat[bi * 4 + pos]);
    return;
  }

  // ---- xpose: x (B,256,56,56) f32 -> Xt[bg][58][58][c=128] bf16, zero borders
  const int bg  = bid / 58;
  const int ihp = bid - bg * 58;
  uint4* dst = (uint4*)(Xt + ((bg * XP + ihp) * XP) * 128);
  if (ihp == 0 || ihp == XP - 1) {
    const uint4 z = {0u, 0u, 0u, 0u};
    for (int i = t; i < XP * 16; i += 256) dst[i] = z;
    return;
  }
  const int ih = ihp - 1;
  const float4* src = (const float4*)(x + (bg * 128) * LOUT + ih * HO);
  for (int i = t; i < 128 * 14; i += 256) {
    int c = i / 14, seg = i - c * 14;                // iw = seg*4
    float4 v = src[c * (LOUT / 4) + seg];
    float* row = &lds[(seg * 4) * 129 + c];
    row[0]       = v.x;
    row[129]     = v.y;
    row[2 * 129] = v.z;
    row[3 * 129] = v.w;
  }
  __syncthreads();
  for (int i = t; i < XP * 16; i += 256) {
    int iwp = i >> 4, oct = i & 15;
    uint4 val = {0u, 0u, 0u, 0u};
    if (iwp != 0 && iwp != XP - 1) {
      const float* s = &lds[(iwp - 1) * 129 + (oct << 3)];
      val.x = cvt_pk_bf16(s[0], s[1]);
      val.y = cvt_pk_bf16(s[2], s[3]);
      val.z = cvt_pk_bf16(s[4], s[5]);
      val.w = cvt_pk_bf16(s[6], s[7]);
    }
    dst[i] = val;
  }
}

// ---------------- conv: implicit-GEMM, BK=64, xor-swizzled LDS (R3) ----------
// LDS row = 64 c = 8 chunks of 16B; chunk (row,ch) stored at slot ch^(row&7).
// Staging: wave issue covers 8 rows x 8 chunks = 1 KB; lane l -> row +(l>>3),
// logical ch (l&7)^(l>>3)  (matches lane-linear LDS dest constraint).
__global__ __launch_bounds__(256, 4) void conv_mfma_kernel(
    const unsigned short* __restrict__ Wt, const unsigned short* __restrict__ Xt,
    float* __restrict__ out) {
  __shared__ __align__(16) unsigned short sA[128 * 64];   // 16 KB
  __shared__ __align__(16) unsigned short sB[128 * 64];   // 16 KB
  const int t  = threadIdx.x;
  const int ln = t & 63, wv = t >> 6;
  const int wm = wv >> 1, wn = wv & 1;
  const int col = ln & 15, kq = ln >> 4, c7 = col & 7;

  // XCD-aware swizzle: contiguous bg range per XCD for L2 locality
  const int lid   = blockIdx.y * 25 + blockIdx.x;
  const int v     = (lid & 7) * 200 + (lid >> 3);
  const int bg    = v / 25;
  const int tileN = v - bg * 25;
  const int g     = bg & 1;
  const int l0    = tileN << 7;

  // staging geometry (fixed per thread)
  const int r8 = ln >> 3;                  // row within 8-row issue group
  const int ch = (ln & 7) ^ r8;            // logical 16B chunk within 64-c row
  int arow[4], brow[4];
  #pragma unroll
  for (int i = 0; i < 4; ++i) {
    const int rr = (wv << 5) + (i << 3) + r8;      // 0..127
    arow[i] = (rr << 7) + (ch << 3);               // of*128 + c
    int ll = l0 + rr;
    if (ll > LOUT - 1) ll = LOUT - 1;              // tail tile: clamp
    int oh = ll / HO, ow = ll - oh * HO;
    brow[i] = ((bg * XP + oh) * XP + ow) * 128 + (ch << 3);
  }

  f32x4 acc[4][4];
  #pragma unroll
  for (int i = 0; i < 4; ++i)
    #pragma unroll
    for (int j = 0; j < 4; ++j) acc[i][j] = (f32x4){0.f, 0.f, 0.f, 0.f};

  for (int tap = 0; tap < 9; ++tap) {
    const int th = tap / 3, tw = tap - th * 3;
    const int bTap = (th * XP + tw) << 7;
    const int aTap = (g * 9 + tap) << 14;
    #pragma unroll 1
    for (int kc = 0; kc < 2; ++kc) {
      const int c0 = kc << 6;
      __syncthreads();                             // prior reads done
      #pragma unroll
      for (int i = 0; i < 4; ++i) {
        const int lb = ((wv << 5) + (i << 3)) << 6;   // LDS elem base
        async_load16(Wt + aTap + c0 + arow[i], &sA[lb]);
        async_load16(Xt + bTap + c0 + brow[i], &sB[lb]);
      }
      __syncthreads();                             // drains vmcnt
      #pragma unroll
      for (int kh = 0; kh < 2; ++kh) {
        const int pk = (((kh << 2) + kq) ^ c7) << 3;   // swizzled chunk offset
        bf16x8 af[4], bfr[4];
        #pragma unroll
        for (int mi = 0; mi < 4; ++mi)
          af[mi] = *(const bf16x8*)&sA[(((wm << 6) + (mi << 4) + col) << 6) + pk];
        #pragma unroll
        for (int ni = 0; ni < 4; ++ni)
          bfr[ni] = *(const bf16x8*)&sB[(((wn << 6) + (ni << 4) + col) << 6) + pk];
        __builtin_amdgcn_s_setprio(1);             // T5: favor MFMA cluster
        #pragma unroll
        for (int mi = 0; mi < 4; ++mi)
          #pragma unroll
          for (int ni = 0; ni < 4; ++ni)
            acc[mi][ni] = __builtin_amdgcn_mfma_f32_16x16x32_bf16(
                af[mi], bfr[ni], acc[mi][ni], 0, 0, 0);
        __builtin_amdgcn_s_setprio(0);
      }
    }
  }

  // epilogue: C/D layout col=lane&15, row=(lane>>4)*4+reg
  const int rowq = kq << 2;
  #pragma unroll
  for (int mi = 0; mi < 4; ++mi) {
    #pragma unroll
    for (int ni = 0; ni < 4; ++ni) {
      const int l = l0 + (wn << 6) + (ni << 4) + col;
      if (l < LOUT) {
        #pragma unroll
        for (int r = 0; r < 4; ++r) {
          const int of = (wm << 6) + (mi << 4) + rowq + r;
          out[(bg * 128 + of) * LOUT + l] = acc[mi][ni][r];
        }
      }
    }
  }
}

extern "C" void kernel_launch(void* const* d_in, const int* in_sizes, int n_in,
                              void* d_out, int out_size, void* d_ws, size_t ws_size,
                              hipStream_t stream) {
  const float* x   = (const float*)d_in[0];
  const float* Ws  = (const float*)d_in[1];
  const float* cw  = (const float*)d_in[2];
  const float* gb  = (const float*)d_in[3];
  const float* pat = (const float*)d_in[4];
  float* out = (float*)d_out;

  unsigned short* Wt = (unsigned short*)d_ws;                       // 576 KB
  unsigned short* Xt = (unsigned short*)((char*)d_ws + (1 << 20));  // 52.6 MB

  prep_kernel<<<4864, 256, 0, stream>>>(x, Ws, cw, gb, pat, Xt, Wt);
  conv_mfma_kernel<<<dim3(25, 64), 256, 0, stream>>>(Wt, Xt, out);
}

// Round 14
// 255.571 us; speedup vs baseline: 1.1378x; 1.0013x over previous
//
#include <hip/hip_runtime.h>

// Sparse 2:4 grouped conv, MI355X.  R14: conv frozen at R13 (= R3 + null-safe
// setprio, 71.3us).  Prep xpose: LDS holds PACKED bf16 iw-pairs (u32) instead
// of f32 — footprint 28.9->14.8 KB (5->8 blocks/CU for latency hiding),
// pass-1 LDS writes halved via v_cvt_pk_bf16_f32, pass-2 re-pairs channels
// with one v_perm_b32 per output word (byte-exact, parity-selected).

#define INF   1152
#define HO    56
#define LOUT  3136      // 56*56
#define XP    58        // padded spatial

typedef __attribute__((ext_vector_type(8))) short bf16x8;
typedef __attribute__((ext_vector_type(4))) float f32x4;

__device__ __forceinline__ unsigned short f2bf(float f) {
  union { float f; unsigned u; } v; v.f = f;
  unsigned r = v.u + 0x7fffu + ((v.u >> 16) & 1u);   // RNE
  return (unsigned short)(r >> 16);
}

__device__ __forceinline__ unsigned cvt_pk_bf16(float lo, float hi) {
  unsigned r;
  asm("v_cvt_pk_bf16_f32 %0, %1, %2" : "=v"(r) : "v"(lo), "v"(hi));
  return r;                                           // lo16=bf16(lo), hi16=bf16(hi)
}

__device__ __forceinline__ void async_load16(const void* g, void* l) {
  __builtin_amdgcn_global_load_lds(
      (const __attribute__((address_space(1))) void*)g,
      (__attribute__((address_space(3))) void*)l, 16, 0, 0);
}

// ---------------- fused prep: pad+transpose+cast x  |  gumbel+mask+pack W ------
// blocks [0,3712): xpose (bg=bid/58, ihp=bid%58) — bf16-packed LDS version
// blocks [3712,4864): Wt[g][tap][of][c] pack with inline gumbel argmax
__global__ __launch_bounds__(256) void prep_kernel(
    const float* __restrict__ x, const float* __restrict__ Ws,
    const float* __restrict__ cw, const float* __restrict__ gb,
    const float* __restrict__ pat,
    unsigned short* __restrict__ Xt, unsigned short* __restrict__ Wt) {
  __shared__ unsigned lds32[28 * 132];               // 14.8 KB: [iw_pair][c]
  const int t   = threadIdx.x;
  const int bid = blockIdx.x;

  if (bid >= 3712) {                                 // ---- weight pack ----
    int idx = (bid - 3712) * 256 + t;                // 294912 total
    int c   = idx & 127;
    int of  = (idx >> 7) & 127;
    int gt  = idx >> 14;                             // g*9+tap
    int g   = gt / 9;
    int tap = gt - g * 9;
    int e   = ((g << 7) + of) * INF + c * 9 + tap;
    int q   = e >> 2, pos = e & 3;
    const float* cq = cw + q * 6;
    const float* gq = gb + q * 6;
    float best = cq[0] + gq[0]; int bi = 0;
    #pragma unroll
    for (int j = 1; j < 6; ++j) {
      float v2 = cq[j] + gq[j];
      if (v2 > best) { best = v2; bi = j; }          // strict > = first-max
    }
    Wt[idx] = f2bf(Ws[e] * pat[bi * 4 + pos]);
    return;
  }

  // ---- xpose: x (B,256,56,56) f32 -> Xt[bg][58][58][c=128] bf16, zero borders
  const int bg  = bid / 58;
  const int ihp = bid - bg * 58;
  uint4* dst = (uint4*)(Xt + ((bg * XP + ihp) * XP) * 128);
  if (ihp == 0 || ihp == XP - 1) {
    const uint4 z = {0u, 0u, 0u, 0u};
    for (int i = t; i < XP * 16; i += 256) dst[i] = z;
    return;
  }
  const int ih = ihp - 1;
  const float4* src = (const float4*)(x + (bg * 128) * LOUT + ih * HO);
  // pass-1: read float4 (4 consecutive iw at channel c), pack iw-pairs to bf16
  for (int i = t; i < 128 * 14; i += 256) {
    int c = i / 14, seg = i - c * 14;                // iw = seg*4 + {0..3}
    float4 v = src[c * (LOUT / 4) + seg];
    lds32[(seg * 2 + 0) * 132 + c] = cvt_pk_bf16(v.x, v.y);  // iw even=lo
    lds32[(seg * 2 + 1) * 132 + c] = cvt_pk_bf16(v.z, v.w);
  }
  __syncthreads();
  // pass-2: for (iwp, oct) gather 8 channels at fixed iw; v_perm re-pairs
  for (int i = t; i < XP * 16; i += 256) {
    int iwp = i >> 4, oct = i & 15;
    uint4 val = {0u, 0u, 0u, 0u};
    if (iwp != 0 && iwp != XP - 1) {
      const int iw   = iwp - 1;
      const int base = (iw >> 1) * 132 + (oct << 3); // 16B-aligned (132%4==0)
      const unsigned sel = (iw & 1) ? 0x07060302u : 0x05040100u;
      uint4 q0 = *(const uint4*)&lds32[base];
      uint4 q1 = *(const uint4*)&lds32[base + 4];
      val.x = __builtin_amdgcn_perm(q0.y, q0.x, sel);
      val.y = __builtin_amdgcn_perm(q0.w, q0.z, sel);
      val.z = __builtin_amdgcn_perm(q1.y, q1.x, sel);
      val.w = __builtin_amdgcn_perm(q1.w, q1.z, sel);
    }
    dst[i] = val;
  }
}

// ---------------- conv: implicit-GEMM, BK=64, xor-swizzled LDS (R3+T5) -------
// LDS row = 64 c = 8 chunks of 16B; chunk (row,ch) stored at slot ch^(row&7).
// Staging: wave issue covers 8 rows x 8 chunks = 1 KB; lane l -> row +(l>>3),
// logical ch (l&7)^(l>>3)  (matches lane-linear LDS dest constraint).
__global__ __launch_bounds__(256, 4) void conv_mfma_kernel(
    const unsigned short* __restrict__ Wt, const unsigned short* __restrict__ Xt,
    float* __restrict__ out) {
  __shared__ __align__(16) unsigned short sA[128 * 64];   // 16 KB
  __shared__ __align__(16) unsigned short sB[128 * 64];   // 16 KB
  const int t  = threadIdx.x;
  const int ln = t & 63, wv = t >> 6;
  const int wm = wv >> 1, wn = wv & 1;
  const int col = ln & 15, kq = ln >> 4, c7 = col & 7;

  // XCD-aware swizzle: contiguous bg range per XCD for L2 locality
  const int lid   = blockIdx.y * 25 + blockIdx.x;
  const int v     = (lid & 7) * 200 + (lid >> 3);
  const int bg    = v / 25;
  const int tileN = v - bg * 25;
  const int g     = bg & 1;
  const int l0    = tileN << 7;

  // staging geometry (fixed per thread)
  const int r8 = ln >> 3;                  // row within 8-row issue group
  const int ch = (ln & 7) ^ r8;            // logical 16B chunk within 64-c row
  int arow[4], brow[4];
  #pragma unroll
  for (int i = 0; i < 4; ++i) {
    const int rr = (wv << 5) + (i << 3) + r8;      // 0..127
    arow[i] = (rr << 7) + (ch << 3);               // of*128 + c
    int ll = l0 + rr;
    if (ll > LOUT - 1) ll = LOUT - 1;              // tail tile: clamp
    int oh = ll / HO, ow = ll - oh * HO;
    brow[i] = ((bg * XP + oh) * XP + ow) * 128 + (ch << 3);
  }

  f32x4 acc[4][4];
  #pragma unroll
  for (int i = 0; i < 4; ++i)
    #pragma unroll
    for (int j = 0; j < 4; ++j) acc[i][j] = (f32x4){0.f, 0.f, 0.f, 0.f};

  for (int tap = 0; tap < 9; ++tap) {
    const int th = tap / 3, tw = tap - th * 3;
    const int bTap = (th * XP + tw) << 7;
    const int aTap = (g * 9 + tap) << 14;
    #pragma unroll 1
    for (int kc = 0; kc < 2; ++kc) {
      const int c0 = kc << 6;
      __syncthreads();                             // prior reads done
      #pragma unroll
      for (int i = 0; i < 4; ++i) {
        const int lb = ((wv << 5) + (i << 3)) << 6;   // LDS elem base
        async_load16(Wt + aTap + c0 + arow[i], &sA[lb]);
        async_load16(Xt + bTap + c0 + brow[i], &sB[lb]);
      }
      __syncthreads();                             // drains vmcnt
      #pragma unroll
      for (int kh = 0; kh < 2; ++kh) {
        const int pk = (((kh << 2) + kq) ^ c7) << 3;   // swizzled chunk offset
        bf16x8 af[4], bfr[4];
        #pragma unroll
        for (int mi = 0; mi < 4; ++mi)
          af[mi] = *(const bf16x8*)&sA[(((wm << 6) + (mi << 4) + col) << 6) + pk];
        #pragma unroll
        for (int ni = 0; ni < 4; ++ni)
          bfr[ni] = *(const bf16x8*)&sB[(((wn << 6) + (ni << 4) + col) << 6) + pk];
        __builtin_amdgcn_s_setprio(1);             // T5 (measured null-safe)
        #pragma unroll
        for (int mi = 0; mi < 4; ++mi)
          #pragma unroll
          for (int ni = 0; ni < 4; ++ni)
            acc[mi][ni] = __builtin_amdgcn_mfma_f32_16x16x32_bf16(
                af[mi], bfr[ni], acc[mi][ni], 0, 0, 0);
        __builtin_amdgcn_s_setprio(0);
      }
    }
  }

  // epilogue: C/D layout col=lane&15, row=(lane>>4)*4+reg
  const int rowq = kq << 2;
  #pragma unroll
  for (int mi = 0; mi < 4; ++mi) {
    #pragma unroll
    for (int ni = 0; ni < 4; ++ni) {
      const int l = l0 + (wn << 6) + (ni << 4) + col;
      if (l < LOUT) {
        #pragma unroll
        for (int r = 0; r < 4; ++r) {
          const int of = (wm << 6) + (mi << 4) + rowq + r;
          out[(bg * 128 + of) * LOUT + l] = acc[mi][ni][r];
        }
      }
    }
  }
}

extern "C" void kernel_launch(void* const* d_in, const int* in_sizes, int n_in,
                              void* d_out, int out_size, void* d_ws, size_t ws_size,
                              hipStream_t stream) {
  const float* x   = (const float*)d_in[0];
  const float* Ws  = (const float*)d_in[1];
  const float* cw  = (const float*)d_in[2];
  const float* gb  = (const float*)d_in[3];
  const float* pat = (const float*)d_in[4];
  float* out = (float*)d_out;

  unsigned short* Wt = (unsigned short*)d_ws;                       // 576 KB
  unsigned short* Xt = (unsigned short*)((char*)d_ws + (1 << 20));  // 52.6 MB

  prep_kernel<<<4864, 256, 0, stream>>>(x, Ws, cw, gb, pat, Xt, Wt);
  conv_mfma_kernel<<<dim3(25, 64), 256, 0, stream>>>(Wt, Xt, out);
}